// Round 1
// baseline (1869.877 us; speedup 1.0000x reference)
//
#include <hip/hip_runtime.h>
#include <hip/hip_bf16.h>

// Problem constants
#define NPTS 131072
#define DIMS 512
#define KC   1024

// c_sq[k] = sum_d centroids[d][k]^2
__global__ void csq_kernel(const float* __restrict__ C, float* __restrict__ csq) {
    int k = blockIdx.x * blockDim.x + threadIdx.x;
    if (k < KC) {
        float s = 0.f;
        for (int d = 0; d < DIMS; ++d) {
            float v = C[d * KC + k];
            s = fmaf(v, v, s);
        }
        csq[k] = s;
    }
}

// Map float to an unsigned int whose unsigned ordering matches float ordering.
__device__ __forceinline__ unsigned int f2o(float f) {
    unsigned int u = __float_as_uint(f);
    return (u & 0x80000000u) ? ~u : (u | 0x80000000u);
}

// Block: 256 threads. Block tile: 64 rows x 256 cols, looped over 4 k-tiles
// (so argmin stays block-local). Thread tile: 8 rows x 8 cols.
// ty = tid>>5 (8 row-groups of 8 rows), tx = tid&31.
// Thread cols within k-tile: {tx*4+j, 128+tx*4+j} -> contiguous wave-wide b128 LDS reads.
__global__ __launch_bounds__(256, 3) void assign_kernel(
    const float* __restrict__ F, const float* __restrict__ C,
    const float* __restrict__ csq, float* __restrict__ out)
{
    __shared__ float At[32][68];          // [d][row], d-major, stride 68 (16B-aligned, bank-skewed)
    __shared__ float Bs[32 * 256];        // [d][k]
    __shared__ unsigned long long best_row[64];

    const int tid = threadIdx.x;
    const int tx = tid & 31;
    const int ty = tid >> 5;
    const int n0 = blockIdx.x * 64;

    if (tid < 64) best_row[tid] = 0xFFFFFFFFFFFFFFFFull;

    unsigned long long best[8];
#pragma unroll
    for (int r = 0; r < 8; ++r) best[r] = 0xFFFFFFFFFFFFFFFFull;

    // A-staging indices: 64 rows x 32 dims = 512 float4, 2 per thread
    const int arow = tid >> 3;   // 0..31 (+32 on second iter)
    const int ac4  = tid & 7;    // 0..7

    const float* Atp = &At[0][ty * 8];
    const float* Bsp = &Bs[tx * 4];

    for (int kt = 0; kt < 4; ++kt) {
        float acc[8][8];
#pragma unroll
        for (int r = 0; r < 8; ++r)
#pragma unroll
            for (int j = 0; j < 8; ++j) acc[r][j] = 0.f;

        for (int dt = 0; dt < DIMS / 32; ++dt) {
            __syncthreads();
            // Stage A (transposed): rows n0..n0+63, dims dt*32..+31
#pragma unroll
            for (int i = 0; i < 2; ++i) {
                int row = arow + 32 * i;
                float4 av = *(const float4*)&F[(long)(n0 + row) * DIMS + dt * 32 + ac4 * 4];
                At[ac4 * 4 + 0][row] = av.x;
                At[ac4 * 4 + 1][row] = av.y;
                At[ac4 * 4 + 2][row] = av.z;
                At[ac4 * 4 + 3][row] = av.w;
            }
            // Stage B: dims dt*32..+31, cols kt*256..+255 (fully coalesced 1KB/wave)
#pragma unroll
            for (int i = 0; i < 8; ++i) {
                int idx = tid + 256 * i;
                int d  = idx >> 6;
                int c4 = idx & 63;
                float4 bv = *(const float4*)&C[(long)(dt * 32 + d) * KC + kt * 256 + c4 * 4];
                *(float4*)&Bs[d * 256 + c4 * 4] = bv;
            }
            __syncthreads();

#pragma unroll 8
            for (int dd = 0; dd < 32; ++dd) {
                float4 a0 = *(const float4*)(Atp + dd * 68);
                float4 a1 = *(const float4*)(Atp + dd * 68 + 4);
                float4 b0 = *(const float4*)(Bsp + dd * 256);
                float4 b1 = *(const float4*)(Bsp + dd * 256 + 128);
                float a[8] = {a0.x, a0.y, a0.z, a0.w, a1.x, a1.y, a1.z, a1.w};
                float b[8] = {b0.x, b0.y, b0.z, b0.w, b1.x, b1.y, b1.z, b1.w};
#pragma unroll
                for (int r = 0; r < 8; ++r)
#pragma unroll
                    for (int j = 0; j < 8; ++j)
                        acc[r][j] = fmaf(a[r], b[j], acc[r][j]);
            }
        }

        // Fused argmin update for this k-tile (keep running best in registers)
        float4 cs0 = *(const float4*)&csq[kt * 256 + tx * 4];
        float4 cs1 = *(const float4*)&csq[kt * 256 + 128 + tx * 4];
        float cs[8] = {cs0.x, cs0.y, cs0.z, cs0.w, cs1.x, cs1.y, cs1.z, cs1.w};
#pragma unroll
        for (int j = 0; j < 8; ++j) {
            int k = kt * 256 + ((j < 4) ? (tx * 4 + j) : (128 + tx * 4 + (j - 4)));
#pragma unroll
            for (int r = 0; r < 8; ++r) {
                float val = cs[j] - 2.0f * acc[r][j];
                unsigned long long key =
                    ((unsigned long long)f2o(val) << 32) | (unsigned long long)(unsigned)k;
                if (key < best[r]) best[r] = key;
            }
        }
    }

#pragma unroll
    for (int r = 0; r < 8; ++r)
        atomicMin(&best_row[ty * 8 + r], best[r]);
    __syncthreads();

    if (tid < 64)
        out[n0 + tid] = (float)(unsigned)(best_row[tid] & 0xFFFFFFFFull);
}

extern "C" void kernel_launch(void* const* d_in, const int* in_sizes, int n_in,
                              void* d_out, int out_size, void* d_ws, size_t ws_size,
                              hipStream_t stream) {
    const float* F = (const float*)d_in[0];   // [NPTS, DIMS]
    const float* C = (const float*)d_in[1];   // [DIMS, KC]
    float* out = (float*)d_out;               // [NPTS]
    float* csq = (float*)d_ws;                // KC floats of scratch

    csq_kernel<<<KC / 256, 256, 0, stream>>>(C, csq);
    assign_kernel<<<NPTS / 64, 256, 0, stream>>>(F, C, csq, out);
}

// Round 3
// 1493.870 us; speedup vs baseline: 1.2517x; 1.2517x over previous
//
#include <hip/hip_runtime.h>
#include <hip/hip_bf16.h>

#define NPTS 131072
#define DIMS 512
#define KC   1024

using bf16x8 = __attribute__((ext_vector_type(8))) __bf16;
using f32x16 = __attribute__((ext_vector_type(16))) float;
typedef unsigned short u16;
typedef unsigned int u32;
typedef unsigned long long u64;

// ---- workspace layout (bytes); total == 271,585,280 (proven available in r2) ----
#define F_HI_OFF   0ull
#define F_LO_OFF   134217728ull                 // 131072*512*2
#define CT_HI_OFF  268435456ull                 // + 131072*512*2
#define CT_LO_OFF  269484032ull                 // + 1024*512*2
#define CSQ_OFF    270532608ull                 // + 1024*512*2
#define G1_OFF     270536704ull                 // + 4096
#define G2_OFF     271060992ull                 // + 524288
#define WS_NEEDED  271585280ull                 // + 524288

#define MARGIN 0.375f

// ---------- helpers ----------
__device__ __forceinline__ u16 f2bf(float v) {
    __hip_bfloat16 h = __float2bfloat16(v);
    return *reinterpret_cast<u16*>(&h);
}
__device__ __forceinline__ float bf2f(u16 u) {
    __hip_bfloat16 h = *reinterpret_cast<__hip_bfloat16*>(&u);
    return __bfloat162float(h);
}
// orderable-uint mapping of float (unsigned compare == float compare)
__device__ __forceinline__ u32 f2o(float f) {
    u32 u = __float_as_uint(f);
    return (u & 0x80000000u) ? ~u : (u | 0x80000000u);
}
__device__ __forceinline__ float o2f(u32 o) {
    u32 u = (o & 0x80000000u) ? (o & 0x7FFFFFFFu) : ~o;
    return __uint_as_float(u);
}
__device__ __forceinline__ u32 umin32(u32 a, u32 b) { return a < b ? a : b; }
__device__ __forceinline__ u32 umax32(u32 a, u32 b) { return a > b ? a : b; }

// global -> LDS direct (16B per lane). LDS dest is wave-uniform base + lane*16.
__device__ __forceinline__ void async_load16(const void* g, const void* l) {
    auto gp = reinterpret_cast<__attribute__((address_space(1))) void*>(
        reinterpret_cast<uintptr_t>(g));
    auto lp = reinterpret_cast<__attribute__((address_space(3))) void*>(
        (unsigned int)reinterpret_cast<uintptr_t>(l));
    __builtin_amdgcn_global_load_lds(gp, lp, 16, 0, 0);
}

// ---------- prepass: split F into hi/lo bf16 ----------
__global__ void split_f_kernel(const float4* __restrict__ F,
                               u16* __restrict__ hi, u16* __restrict__ lo) {
    size_t i = (size_t)blockIdx.x * 256 + threadIdx.x;   // 8 floats per thread
    float4 a = F[2 * i], b = F[2 * i + 1];
    float v[8] = {a.x, a.y, a.z, a.w, b.x, b.y, b.z, b.w};
    u16 h[8], l[8];
#pragma unroll
    for (int j = 0; j < 8; ++j) {
        h[j] = f2bf(v[j]);
        l[j] = f2bf(v[j] - bf2f(h[j]));
    }
    ushort4* hp = (ushort4*)(hi + 8 * i);
    ushort4* lp = (ushort4*)(lo + 8 * i);
    hp[0] = make_ushort4(h[0], h[1], h[2], h[3]);
    hp[1] = make_ushort4(h[4], h[5], h[6], h[7]);
    lp[0] = make_ushort4(l[0], l[1], l[2], l[3]);
    lp[1] = make_ushort4(l[4], l[5], l[6], l[7]);
}

// ---------- prepass: transpose C [512][1024] -> Ct [1024][512], split hi/lo ----------
__global__ void split_c_kernel(const float* __restrict__ C,
                               u16* __restrict__ hi, u16* __restrict__ lo) {
    __shared__ float t[32][33];
    int bn = blockIdx.x, bd = blockIdx.y;
    int tx = threadIdx.x & 31, ty = threadIdx.x >> 5;
#pragma unroll
    for (int r = 0; r < 32; r += 8)
        t[ty + r][tx] = C[(size_t)(bd * 32 + ty + r) * KC + bn * 32 + tx];
    __syncthreads();
#pragma unroll
    for (int r = 0; r < 32; r += 8) {
        int n = bn * 32 + ty + r, d = bd * 32 + tx;
        float v = t[tx][ty + r];
        u16 h = f2bf(v);
        u16 l = f2bf(v - bf2f(h));
        hi[(size_t)n * DIMS + d] = h;
        lo[(size_t)n * DIMS + d] = l;
    }
}

// ---------- c_sq ----------
__global__ void csq_kernel(const float* __restrict__ C, float* __restrict__ csq) {
    int k = blockIdx.x * blockDim.x + threadIdx.x;
    if (k < KC) {
        float s = 0.f;
        for (int d = 0; d < DIMS; ++d) {
            float v = C[d * KC + k];
            s = fmaf(v, v, s);
        }
        csq[k] = s;
    }
}

// ---------- main: bf16x4 MFMA GEMM + block top-2 + global streaming top-2 ----------
// block tile 128(M) x 128(N), BK=32, 4 waves each 64x64 (2x2 of 32x32x16 MFMA)
// LDS: A_HI[0,8K) A_LO[8K,16K) B_HI[16K,24K) B_LO[24K,32K)
// tile chunk layout: chunk(m,c) at m*4 + (c ^ ((m>>1)&3)), 16B chunks
__global__ __launch_bounds__(256, 3) void gemm_argmin_kernel(
    const u16* __restrict__ Fhi, const u16* __restrict__ Flo,
    const u16* __restrict__ Cthi, const u16* __restrict__ Ctlo,
    const float* __restrict__ csq, u32* __restrict__ g1, u32* __restrict__ g2)
{
    __shared__ uint8_t smem[32768];
    __shared__ u32 tbl[128][2][2];    // [row][wave-wn][top2]

    const int tid  = threadIdx.x;
    const int lane = tid & 63;
    const int wid  = tid >> 6;
    const int wm   = wid >> 1, wn = wid & 1;
    const int bx   = blockIdx.x;     // col tile 0..7
    const int by   = blockIdx.y;     // row tile 0..1023

    f32x16 acc[2][2];
#pragma unroll
    for (int i = 0; i < 2; ++i)
#pragma unroll
        for (int j = 0; j < 2; ++j)
#pragma unroll
            for (int e = 0; e < 16; ++e) acc[i][j][e] = 0.f;

    // staging: lane -> (row r0+(lane>>2), chunk c_st), c_st = (lane&3)^((lane>>3)&3)
    const int c_st = (lane & 3) ^ ((lane >> 3) & 3);
    const size_t arow = (size_t)(by * 128 + wid * 32 + (lane >> 2)) * DIMS + c_st * 8;
    const size_t brow = (size_t)(bx * 128 + wid * 32 + (lane >> 2)) * DIMS + c_st * 8;
    const u16* aH = Fhi  + arow;
    const u16* aL = Flo  + arow;
    const u16* bH = Cthi + brow;
    const u16* bL = Ctlo + brow;
    const unsigned lds_w = wid * 2048;

    // fragment read offsets
    const int h  = lane >> 5;
    const int xr = (lane >> 1) & 3;
    const unsigned mb = (unsigned)(lane & 31) * 64;
    const unsigned offs0 = mb + (unsigned)(((0 + h) ^ xr) * 16);
    const unsigned offs1 = mb + (unsigned)(((2 + h) ^ xr) * 16);
    const unsigned aoff0 = wm * 4096 + offs0, aoff1 = wm * 4096 + offs1;
    const unsigned boff0 = 16384 + wn * 4096 + offs0, boff1 = 16384 + wn * 4096 + offs1;

    for (int kt = 0; kt < DIMS / 32; ++kt) {
        const int k0 = kt * 32;
        __syncthreads();
        async_load16(aH + k0,             smem + lds_w);
        async_load16(aH + 16 * DIMS + k0, smem + lds_w + 1024);
        async_load16(aL + k0,             smem + 8192 + lds_w);
        async_load16(aL + 16 * DIMS + k0, smem + 8192 + lds_w + 1024);
        async_load16(bH + k0,             smem + 16384 + lds_w);
        async_load16(bH + 16 * DIMS + k0, smem + 16384 + lds_w + 1024);
        async_load16(bL + k0,             smem + 24576 + lds_w);
        async_load16(bL + 16 * DIMS + k0, smem + 24576 + lds_w + 1024);
        __syncthreads();

#pragma unroll
        for (int s = 0; s < 2; ++s) {
            const unsigned ao = s ? aoff1 : aoff0;
            const unsigned bo = s ? boff1 : boff0;
            bf16x8 ah[2], al[2], bh[2], bl[2];
#pragma unroll
            for (int mt = 0; mt < 2; ++mt) {
                ah[mt] = *(const bf16x8*)(smem + ao + mt * 2048);
                al[mt] = *(const bf16x8*)(smem + 8192 + ao + mt * 2048);
            }
#pragma unroll
            for (int nt = 0; nt < 2; ++nt) {
                bh[nt] = *(const bf16x8*)(smem + bo + nt * 2048);
                bl[nt] = *(const bf16x8*)(smem + 8192 + bo + nt * 2048);
            }
#pragma unroll
            for (int mt = 0; mt < 2; ++mt)
#pragma unroll
                for (int nt = 0; nt < 2; ++nt) {
                    acc[mt][nt] = __builtin_amdgcn_mfma_f32_32x32x16_bf16(ah[mt], bh[nt], acc[mt][nt], 0, 0, 0);
                    acc[mt][nt] = __builtin_amdgcn_mfma_f32_32x32x16_bf16(ah[mt], bl[nt], acc[mt][nt], 0, 0, 0);
                    acc[mt][nt] = __builtin_amdgcn_mfma_f32_32x32x16_bf16(al[mt], bh[nt], acc[mt][nt], 0, 0, 0);
                    acc[mt][nt] = __builtin_amdgcn_mfma_f32_32x32x16_bf16(al[mt], bl[nt], acc[mt][nt], 0, 0, 0);
                }
        }
    }

    // --- epilogue: per-row block-local top-2 (u32 keys: dist-top22 | col-10) ---
    // C/D layout: col = lane&31, row = (reg&3) + 8*(reg>>2) + 4*(lane>>5)
    const int cl = lane & 31;
    const int colbase = bx * 128 + wn * 64 + cl;
    const float cs0 = csq[colbase], cs1 = csq[colbase + 32];

#pragma unroll
    for (int mt = 0; mt < 2; ++mt)
#pragma unroll
        for (int reg = 0; reg < 16; ++reg) {
            const int row = wm * 64 + mt * 32 + (reg & 3) + 8 * (reg >> 2) + 4 * h;
            float d0 = cs0 - 2.0f * acc[mt][0][reg];
            float d1 = cs1 - 2.0f * acc[mt][1][reg];
            u32 k0 = (f2o(d0) & 0xFFFFFC00u) | (u32)colbase;
            u32 k1 = (f2o(d1) & 0xFFFFFC00u) | (u32)(colbase + 32);
            u32 a = umin32(k0, k1), b = umax32(k0, k1);   // sorted pair
#pragma unroll
            for (int off = 16; off > 0; off >>= 1) {      // stays within 32-lane half
                u32 oa = __shfl_xor(a, off, 64);
                u32 ob = __shfl_xor(b, off, 64);
                u32 lo = umin32(a, oa), hi = umax32(a, oa);
                b = umin32(hi, umin32(b, ob));
                a = lo;
            }
            if (cl == 0) { tbl[row][wn][0] = a; tbl[row][wn][1] = b; }
        }
    __syncthreads();

    if (tid < 128) {
        const u32 a0 = tbl[tid][0][0], b0 = tbl[tid][0][1];
        const u32 a1 = tbl[tid][1][0], b1 = tbl[tid][1][1];
        u32 m1 = umin32(a0, a1);
        u32 m2 = umin32(umax32(a0, a1), umin32(b0, b1));
        const size_t grow = (size_t)by * 128 + tid;
        // exact streaming top-2 automaton over quantized keys
        u32 o = atomicMin(&g1[grow], m1);
        atomicMin(&g2[grow], (m1 < o) ? o : m1);
        atomicMin(&g2[grow], m2);
    }
}

// ---------- finalize + exact fp32 rescue ----------
// 256 blocks; each owns 512 consecutive rows: writes non-flagged outputs,
// batches flagged rows x16 and recomputes exact fp32 argmin for them.
__global__ __launch_bounds__(256) void rescue_finalize_kernel(
    const float* __restrict__ F, const float* __restrict__ C,
    const float* __restrict__ csq, const u32* __restrict__ g1,
    const u32* __restrict__ g2, float* __restrict__ out)
{
    __shared__ u32 list[512];
    __shared__ int cnt;
    __shared__ float xs[16][512];
    __shared__ u64 winner[16];

    const int tid = threadIdx.x;
    const int base = blockIdx.x * 512;
    if (tid == 0) cnt = 0;
    __syncthreads();

    for (int i = tid; i < 512; i += 256) {
        const int row = base + i;
        const u32 k1 = g1[row], k2 = g2[row];
        const float d1 = o2f(k1 & 0xFFFFFC00u);
        const float d2 = o2f(k2 & 0xFFFFFC00u);
        if (d2 - d1 > MARGIN) {
            out[row] = (float)(k1 & 1023u);
        } else {
            int idx = atomicAdd(&cnt, 1);
            list[idx] = (u32)row;
        }
    }
    __syncthreads();

    const int n = cnt;
    for (int b = 0; b < n; b += 16) {
        __syncthreads();
        if (tid < 16) winner[tid] = ~0ull;
#pragma unroll
        for (int j = 0; j < 16; ++j) {
            if (b + j < n) {
                const size_t row = list[b + j];
                for (int i = tid; i < 512; i += 256)
                    xs[j][i] = F[row * DIMS + i];
            }
        }
        __syncthreads();

        float dot[16][4];
#pragma unroll
        for (int j = 0; j < 16; ++j)
#pragma unroll
            for (int q = 0; q < 4; ++q) dot[j][q] = 0.f;

        for (int d = 0; d < DIMS; ++d) {
            float cv[4];
#pragma unroll
            for (int q = 0; q < 4; ++q) cv[q] = C[d * KC + tid + 256 * q];
#pragma unroll
            for (int j = 0; j < 16; ++j) {
                const float x = xs[j][d];
#pragma unroll
                for (int q = 0; q < 4; ++q)
                    dot[j][q] = fmaf(x, cv[q], dot[j][q]);
            }
        }

#pragma unroll
        for (int j = 0; j < 16; ++j) {
#pragma unroll
            for (int q = 0; q < 4; ++q) {
                const int k = tid + 256 * q;
                const float dist = csq[k] - 2.0f * dot[j][q];
                const u64 key = ((u64)f2o(dist) << 32) | (u32)k;  // ties -> smallest k
                atomicMin(&winner[j], key);
            }
        }
        __syncthreads();
        if (tid < 16 && b + tid < n)
            out[list[b + tid]] = (float)(u32)(winner[tid] & 0xFFFFFFFFull);
    }
}

// ================= fallback (round-1 fp32, used only if ws too small) =================
__global__ __launch_bounds__(256, 3) void assign_kernel_fp32(
    const float* __restrict__ F, const float* __restrict__ C,
    const float* __restrict__ csq, float* __restrict__ out)
{
    __shared__ float At[32][68];
    __shared__ float Bs[32 * 256];
    __shared__ u64 best_row[64];

    const int tid = threadIdx.x;
    const int tx = tid & 31;
    const int ty = tid >> 5;
    const int n0 = blockIdx.x * 64;

    if (tid < 64) best_row[tid] = ~0ull;

    u64 best[8];
#pragma unroll
    for (int r = 0; r < 8; ++r) best[r] = ~0ull;

    const int arow = tid >> 3;
    const int ac4  = tid & 7;
    const float* Atp = &At[0][ty * 8];
    const float* Bsp = &Bs[tx * 4];

    for (int kt = 0; kt < 4; ++kt) {
        float acc[8][8];
#pragma unroll
        for (int r = 0; r < 8; ++r)
#pragma unroll
            for (int j = 0; j < 8; ++j) acc[r][j] = 0.f;

        for (int dt = 0; dt < DIMS / 32; ++dt) {
            __syncthreads();
#pragma unroll
            for (int i = 0; i < 2; ++i) {
                int row = arow + 32 * i;
                float4 av = *(const float4*)&F[(long)(n0 + row) * DIMS + dt * 32 + ac4 * 4];
                At[ac4 * 4 + 0][row] = av.x;
                At[ac4 * 4 + 1][row] = av.y;
                At[ac4 * 4 + 2][row] = av.z;
                At[ac4 * 4 + 3][row] = av.w;
            }
#pragma unroll
            for (int i = 0; i < 8; ++i) {
                int idx = tid + 256 * i;
                int d  = idx >> 6;
                int c4 = idx & 63;
                float4 bv = *(const float4*)&C[(long)(dt * 32 + d) * KC + kt * 256 + c4 * 4];
                *(float4*)&Bs[d * 256 + c4 * 4] = bv;
            }
            __syncthreads();

#pragma unroll 8
            for (int dd = 0; dd < 32; ++dd) {
                float4 a0 = *(const float4*)(Atp + dd * 68);
                float4 a1 = *(const float4*)(Atp + dd * 68 + 4);
                float4 b0 = *(const float4*)(Bsp + dd * 256);
                float4 b1 = *(const float4*)(Bsp + dd * 256 + 128);
                float a[8] = {a0.x, a0.y, a0.z, a0.w, a1.x, a1.y, a1.z, a1.w};
                float bb[8] = {b0.x, b0.y, b0.z, b0.w, b1.x, b1.y, b1.z, b1.w};
#pragma unroll
                for (int r = 0; r < 8; ++r)
#pragma unroll
                    for (int j = 0; j < 8; ++j)
                        acc[r][j] = fmaf(a[r], bb[j], acc[r][j]);
            }
        }

        float4 cs0 = *(const float4*)&csq[kt * 256 + tx * 4];
        float4 cs1 = *(const float4*)&csq[kt * 256 + 128 + tx * 4];
        float cs[8] = {cs0.x, cs0.y, cs0.z, cs0.w, cs1.x, cs1.y, cs1.z, cs1.w};
#pragma unroll
        for (int j = 0; j < 8; ++j) {
            int k = kt * 256 + ((j < 4) ? (tx * 4 + j) : (128 + tx * 4 + (j - 4)));
#pragma unroll
            for (int r = 0; r < 8; ++r) {
                float val = cs[j] - 2.0f * acc[r][j];
                u64 key = ((u64)f2o(val) << 32) | (u64)(unsigned)k;
                if (key < best[r]) best[r] = key;
            }
        }
    }

#pragma unroll
    for (int r = 0; r < 8; ++r)
        atomicMin(&best_row[ty * 8 + r], best[r]);
    __syncthreads();

    if (tid < 64)
        out[n0 + tid] = (float)(unsigned)(best_row[tid] & 0xFFFFFFFFull);
}

// ================= launch =================
extern "C" void kernel_launch(void* const* d_in, const int* in_sizes, int n_in,
                              void* d_out, int out_size, void* d_ws, size_t ws_size,
                              hipStream_t stream) {
    const float* F = (const float*)d_in[0];   // [131072, 512]
    const float* C = (const float*)d_in[1];   // [512, 1024]
    float* out = (float*)d_out;               // [131072]
    char* ws = (char*)d_ws;

    if (ws_size < WS_NEEDED) {
        float* csq = (float*)d_ws;
        csq_kernel<<<KC / 256, 256, 0, stream>>>(C, csq);
        assign_kernel_fp32<<<NPTS / 64, 256, 0, stream>>>(F, C, csq, out);
        return;
    }

    u16* Fhi  = (u16*)(ws + F_HI_OFF);
    u16* Flo  = (u16*)(ws + F_LO_OFF);
    u16* Cthi = (u16*)(ws + CT_HI_OFF);
    u16* Ctlo = (u16*)(ws + CT_LO_OFF);
    float* csq = (float*)(ws + CSQ_OFF);
    u32* g1 = (u32*)(ws + G1_OFF);
    u32* g2 = (u32*)(ws + G2_OFF);

    split_f_kernel<<<NPTS * DIMS / 8 / 256, 256, 0, stream>>>((const float4*)F, Fhi, Flo);
    split_c_kernel<<<dim3(KC / 32, DIMS / 32), 256, 0, stream>>>(C, Cthi, Ctlo);
    csq_kernel<<<KC / 256, 256, 0, stream>>>(C, csq);
    hipMemsetAsync(g1, 0xFF, 2ull * NPTS * 4, stream);
    gemm_argmin_kernel<<<dim3(KC / 128, NPTS / 128), 256, 0, stream>>>(Fhi, Flo, Cthi, Ctlo, csq, g1, g2);
    rescue_finalize_kernel<<<256, 256, 0, stream>>>(F, C, csq, g1, g2, out);
}

// Round 4
// 1034.422 us; speedup vs baseline: 1.8077x; 1.4442x over previous
//
#include <hip/hip_runtime.h>
#include <hip/hip_bf16.h>

#define NPTS 131072
#define DIMS 512
#define KC   1024

using bf16x8 = __attribute__((ext_vector_type(8))) __bf16;
using f32x16 = __attribute__((ext_vector_type(16))) float;
typedef unsigned short u16;
typedef unsigned int u32;
typedef unsigned long long u64;

// ---- workspace layout (bytes); total == 271,585,280 (proven available) ----
#define F_HI_OFF   0ull
#define F_LO_OFF   134217728ull                 // 131072*512*2
#define CT_HI_OFF  268435456ull                 // + 131072*512*2
#define CT_LO_OFF  269484032ull                 // + 1024*512*2
#define CSQ_OFF    270532608ull                 // + 1024*512*2
#define G1_OFF     270536704ull                 // + 4096
#define G2_OFF     271060992ull                 // + 524288
#define WS_NEEDED  271585280ull                 // + 524288
// overlay (valid only AFTER gemm_argmin: Fhi region is dead)
#define CNT_OFF    0ull                         // [0]=list count, [1]=work ptr
#define LIST_OFF   256ull                       // u32 x up to 131072

#define MARGIN 0.375f

// ---------- helpers ----------
__device__ __forceinline__ u16 f2bf(float v) {
    __hip_bfloat16 h = __float2bfloat16(v);
    return *reinterpret_cast<u16*>(&h);
}
__device__ __forceinline__ float bf2f(u16 u) {
    __hip_bfloat16 h = *reinterpret_cast<__hip_bfloat16*>(&u);
    return __bfloat162float(h);
}
__device__ __forceinline__ u32 f2o(float f) {
    u32 u = __float_as_uint(f);
    return (u & 0x80000000u) ? ~u : (u | 0x80000000u);
}
__device__ __forceinline__ float o2f(u32 o) {
    u32 u = (o & 0x80000000u) ? (o & 0x7FFFFFFFu) : ~o;
    return __uint_as_float(u);
}
__device__ __forceinline__ u32 umin32(u32 a, u32 b) { return a < b ? a : b; }
__device__ __forceinline__ u32 umax32(u32 a, u32 b) { return a > b ? a : b; }
__device__ __forceinline__ u64 umin64(u64 a, u64 b) { return a < b ? a : b; }

__device__ __forceinline__ void async_load16(const void* g, const void* l) {
    auto gp = reinterpret_cast<__attribute__((address_space(1))) void*>(
        reinterpret_cast<uintptr_t>(g));
    auto lp = reinterpret_cast<__attribute__((address_space(3))) void*>(
        (unsigned int)reinterpret_cast<uintptr_t>(l));
    __builtin_amdgcn_global_load_lds(gp, lp, 16, 0, 0);
}

// ---------- prepass: split F into hi/lo bf16 ----------
__global__ void split_f_kernel(const float4* __restrict__ F,
                               u16* __restrict__ hi, u16* __restrict__ lo) {
    size_t i = (size_t)blockIdx.x * 256 + threadIdx.x;
    float4 a = F[2 * i], b = F[2 * i + 1];
    float v[8] = {a.x, a.y, a.z, a.w, b.x, b.y, b.z, b.w};
    u16 h[8], l[8];
#pragma unroll
    for (int j = 0; j < 8; ++j) {
        h[j] = f2bf(v[j]);
        l[j] = f2bf(v[j] - bf2f(h[j]));
    }
    ushort4* hp = (ushort4*)(hi + 8 * i);
    ushort4* lp = (ushort4*)(lo + 8 * i);
    hp[0] = make_ushort4(h[0], h[1], h[2], h[3]);
    hp[1] = make_ushort4(h[4], h[5], h[6], h[7]);
    lp[0] = make_ushort4(l[0], l[1], l[2], l[3]);
    lp[1] = make_ushort4(l[4], l[5], l[6], l[7]);
}

// ---------- prepass: transpose C -> Ct [1024][512], split hi/lo ----------
__global__ void split_c_kernel(const float* __restrict__ C,
                               u16* __restrict__ hi, u16* __restrict__ lo) {
    __shared__ float t[32][33];
    int bn = blockIdx.x, bd = blockIdx.y;
    int tx = threadIdx.x & 31, ty = threadIdx.x >> 5;
#pragma unroll
    for (int r = 0; r < 32; r += 8)
        t[ty + r][tx] = C[(size_t)(bd * 32 + ty + r) * KC + bn * 32 + tx];
    __syncthreads();
#pragma unroll
    for (int r = 0; r < 32; r += 8) {
        int n = bn * 32 + ty + r, d = bd * 32 + tx;
        float v = t[tx][ty + r];
        u16 h = f2bf(v);
        u16 l = f2bf(v - bf2f(h));
        hi[(size_t)n * DIMS + d] = h;
        lo[(size_t)n * DIMS + d] = l;
    }
}

// ---------- c_sq ----------
__global__ void csq_kernel(const float* __restrict__ C, float* __restrict__ csq) {
    int k = blockIdx.x * blockDim.x + threadIdx.x;
    if (k < KC) {
        float s = 0.f;
        for (int d = 0; d < DIMS; ++d) {
            float v = C[d * KC + k];
            s = fmaf(v, v, s);
        }
        csq[k] = s;
    }
}

// ---------- main: bf16x4 MFMA GEMM + block top-2 + global streaming top-2 ----------
__global__ __launch_bounds__(256, 3) void gemm_argmin_kernel(
    const u16* __restrict__ Fhi, const u16* __restrict__ Flo,
    const u16* __restrict__ Cthi, const u16* __restrict__ Ctlo,
    const float* __restrict__ csq, u32* __restrict__ g1, u32* __restrict__ g2)
{
    __shared__ uint8_t smem[32768];
    __shared__ u32 tbl[128][2][2];

    const int tid  = threadIdx.x;
    const int lane = tid & 63;
    const int wid  = tid >> 6;
    const int wm   = wid >> 1, wn = wid & 1;
    const int bx   = blockIdx.x;
    const int by   = blockIdx.y;

    f32x16 acc[2][2];
#pragma unroll
    for (int i = 0; i < 2; ++i)
#pragma unroll
        for (int j = 0; j < 2; ++j)
#pragma unroll
            for (int e = 0; e < 16; ++e) acc[i][j][e] = 0.f;

    const int c_st = (lane & 3) ^ ((lane >> 3) & 3);
    const size_t arow = (size_t)(by * 128 + wid * 32 + (lane >> 2)) * DIMS + c_st * 8;
    const size_t brow = (size_t)(bx * 128 + wid * 32 + (lane >> 2)) * DIMS + c_st * 8;
    const u16* aH = Fhi  + arow;
    const u16* aL = Flo  + arow;
    const u16* bH = Cthi + brow;
    const u16* bL = Ctlo + brow;
    const unsigned lds_w = wid * 2048;

    const int h  = lane >> 5;
    const int xr = (lane >> 1) & 3;
    const unsigned mb = (unsigned)(lane & 31) * 64;
    const unsigned offs0 = mb + (unsigned)(((0 + h) ^ xr) * 16);
    const unsigned offs1 = mb + (unsigned)(((2 + h) ^ xr) * 16);
    const unsigned aoff0 = wm * 4096 + offs0, aoff1 = wm * 4096 + offs1;
    const unsigned boff0 = 16384 + wn * 4096 + offs0, boff1 = 16384 + wn * 4096 + offs1;

    for (int kt = 0; kt < DIMS / 32; ++kt) {
        const int k0 = kt * 32;
        __syncthreads();
        async_load16(aH + k0,             smem + lds_w);
        async_load16(aH + 16 * DIMS + k0, smem + lds_w + 1024);
        async_load16(aL + k0,             smem + 8192 + lds_w);
        async_load16(aL + 16 * DIMS + k0, smem + 8192 + lds_w + 1024);
        async_load16(bH + k0,             smem + 16384 + lds_w);
        async_load16(bH + 16 * DIMS + k0, smem + 16384 + lds_w + 1024);
        async_load16(bL + k0,             smem + 24576 + lds_w);
        async_load16(bL + 16 * DIMS + k0, smem + 24576 + lds_w + 1024);
        __syncthreads();

#pragma unroll
        for (int s = 0; s < 2; ++s) {
            const unsigned ao = s ? aoff1 : aoff0;
            const unsigned bo = s ? boff1 : boff0;
            bf16x8 ah[2], al[2], bh[2], bl[2];
#pragma unroll
            for (int mt = 0; mt < 2; ++mt) {
                ah[mt] = *(const bf16x8*)(smem + ao + mt * 2048);
                al[mt] = *(const bf16x8*)(smem + 8192 + ao + mt * 2048);
            }
#pragma unroll
            for (int nt = 0; nt < 2; ++nt) {
                bh[nt] = *(const bf16x8*)(smem + bo + nt * 2048);
                bl[nt] = *(const bf16x8*)(smem + 8192 + bo + nt * 2048);
            }
#pragma unroll
            for (int mt = 0; mt < 2; ++mt)
#pragma unroll
                for (int nt = 0; nt < 2; ++nt) {
                    acc[mt][nt] = __builtin_amdgcn_mfma_f32_32x32x16_bf16(ah[mt], bh[nt], acc[mt][nt], 0, 0, 0);
                    acc[mt][nt] = __builtin_amdgcn_mfma_f32_32x32x16_bf16(ah[mt], bl[nt], acc[mt][nt], 0, 0, 0);
                    acc[mt][nt] = __builtin_amdgcn_mfma_f32_32x32x16_bf16(al[mt], bh[nt], acc[mt][nt], 0, 0, 0);
                    acc[mt][nt] = __builtin_amdgcn_mfma_f32_32x32x16_bf16(al[mt], bl[nt], acc[mt][nt], 0, 0, 0);
                }
        }
    }

    const int cl = lane & 31;
    const int colbase = bx * 128 + wn * 64 + cl;
    const float cs0 = csq[colbase], cs1 = csq[colbase + 32];

#pragma unroll
    for (int mt = 0; mt < 2; ++mt)
#pragma unroll
        for (int reg = 0; reg < 16; ++reg) {
            const int row = wm * 64 + mt * 32 + (reg & 3) + 8 * (reg >> 2) + 4 * h;
            float d0 = cs0 - 2.0f * acc[mt][0][reg];
            float d1 = cs1 - 2.0f * acc[mt][1][reg];
            u32 k0 = (f2o(d0) & 0xFFFFFC00u) | (u32)colbase;
            u32 k1 = (f2o(d1) & 0xFFFFFC00u) | (u32)(colbase + 32);
            u32 a = umin32(k0, k1), b = umax32(k0, k1);
#pragma unroll
            for (int off = 16; off > 0; off >>= 1) {
                u32 oa = __shfl_xor(a, off, 64);
                u32 ob = __shfl_xor(b, off, 64);
                u32 lo = umin32(a, oa), hi = umax32(a, oa);
                b = umin32(hi, umin32(b, ob));
                a = lo;
            }
            if (cl == 0) { tbl[row][wn][0] = a; tbl[row][wn][1] = b; }
        }
    __syncthreads();

    if (tid < 128) {
        const u32 a0 = tbl[tid][0][0], b0 = tbl[tid][0][1];
        const u32 a1 = tbl[tid][1][0], b1 = tbl[tid][1][1];
        u32 m1 = umin32(a0, a1);
        u32 m2 = umin32(umax32(a0, a1), umin32(b0, b1));
        const size_t grow = (size_t)by * 128 + tid;
        u32 o = atomicMin(&g1[grow], m1);
        atomicMin(&g2[grow], (m1 < o) ? o : m1);
        atomicMin(&g2[grow], m2);
    }
}

// ---------- phase A: flag rows; write confident outputs; compact doubtful rows ----------
__global__ __launch_bounds__(256) void flag_compact_kernel(
    const u32* __restrict__ g1, const u32* __restrict__ g2,
    float* __restrict__ out, u32* __restrict__ cnt, u32* __restrict__ list)
{
    const int row = blockIdx.x * 256 + threadIdx.x;
    const u32 k1 = g1[row], k2 = g2[row];
    const float d1 = o2f(k1 & 0xFFFFFC00u);
    const float d2 = o2f(k2 & 0xFFFFFC00u);
    if (d2 - d1 > MARGIN) {
        out[row] = (float)(k1 & 1023u);
    } else {
        u32 idx = atomicAdd(cnt, 1u);
        list[idx] = (u32)row;
    }
}

// ---------- phase B: exact fp32 argmin for flagged rows (work-stealing, 4 rows/batch) ----------
// per thread: dot[4 rows][4 cols] = 16 accumulators -> no spill
__global__ __launch_bounds__(256) void rescue2_kernel(
    const float* __restrict__ F, const float* __restrict__ C,
    const float* __restrict__ csq, const u32* __restrict__ cnt_list,
    u32* __restrict__ wptr, float* __restrict__ out)
{
    __shared__ float xs[4][512];
    __shared__ u64 wavemin[4][4];
    __shared__ int rows_s[4];

    const int tid = threadIdx.x;
    const int lane = tid & 63;
    const int wid = tid >> 6;
    const u32 n = cnt_list[0];          // list count (cnt at CNT_OFF, list at LIST_OFF)
    const u32* list = cnt_list + 64;    // LIST_OFF - CNT_OFF = 256 B = 64 u32

    for (;;) {
        __syncthreads();
        u32 base;
        if (tid == 0) {
            base = atomicAdd(wptr, 4u);
            rows_s[0] = (int)base;
        }
        __syncthreads();
        base = (u32)rows_s[0];
        if (base >= n) break;

        int rows[4];
#pragma unroll
        for (int j = 0; j < 4; ++j) {
            u32 idx = base + j;
            rows[j] = (int)list[idx < n ? idx : (n - 1)];
        }
        // stage 4 rows into LDS (coalesced float4)
#pragma unroll
        for (int j = 0; j < 4; ++j) {
            if (tid < 128)
                *(float4*)&xs[j][tid * 4] = *(const float4*)&F[(size_t)rows[j] * DIMS + tid * 4];
        }
        __syncthreads();

        float dot[4][4];
#pragma unroll
        for (int j = 0; j < 4; ++j)
#pragma unroll
            for (int q = 0; q < 4; ++q) dot[j][q] = 0.f;

#pragma unroll 4
        for (int d = 0; d < DIMS; ++d) {
            float cv[4];
#pragma unroll
            for (int q = 0; q < 4; ++q) cv[q] = C[d * KC + tid + 256 * q];
            float xv[4];
#pragma unroll
            for (int j = 0; j < 4; ++j) xv[j] = xs[j][d];
#pragma unroll
            for (int j = 0; j < 4; ++j)
#pragma unroll
                for (int q = 0; q < 4; ++q)
                    dot[j][q] = fmaf(xv[j], cv[q], dot[j][q]);
        }

#pragma unroll
        for (int j = 0; j < 4; ++j) {
            u64 best = ~0ull;
#pragma unroll
            for (int q = 0; q < 4; ++q) {
                const int k = tid + 256 * q;
                const float dist = csq[k] - 2.0f * dot[j][q];
                best = umin64(best, ((u64)f2o(dist) << 32) | (u32)k);
            }
#pragma unroll
            for (int off = 32; off > 0; off >>= 1)
                best = umin64(best, __shfl_xor(best, off, 64));
            if (lane == 0) wavemin[j][wid] = best;
        }
        __syncthreads();
        if (tid < 4) {
            const u32 idx = base + tid;
            if (idx < n) {
                u64 b = umin64(umin64(wavemin[tid][0], wavemin[tid][1]),
                               umin64(wavemin[tid][2], wavemin[tid][3]));
                out[list[idx]] = (float)(u32)(b & 0xFFFFFFFFull);
            }
        }
    }
}

// ================= fallback (fp32 vector path, used only if ws too small) =================
__global__ __launch_bounds__(256, 3) void assign_kernel_fp32(
    const float* __restrict__ F, const float* __restrict__ C,
    const float* __restrict__ csq, float* __restrict__ out)
{
    __shared__ float At[32][68];
    __shared__ float Bs[32 * 256];
    __shared__ u64 best_row[64];

    const int tid = threadIdx.x;
    const int tx = tid & 31;
    const int ty = tid >> 5;
    const int n0 = blockIdx.x * 64;

    if (tid < 64) best_row[tid] = ~0ull;

    u64 best[8];
#pragma unroll
    for (int r = 0; r < 8; ++r) best[r] = ~0ull;

    const int arow = tid >> 3;
    const int ac4  = tid & 7;
    const float* Atp = &At[0][ty * 8];
    const float* Bsp = &Bs[tx * 4];

    for (int kt = 0; kt < 4; ++kt) {
        float acc[8][8];
#pragma unroll
        for (int r = 0; r < 8; ++r)
#pragma unroll
            for (int j = 0; j < 8; ++j) acc[r][j] = 0.f;

        for (int dt = 0; dt < DIMS / 32; ++dt) {
            __syncthreads();
#pragma unroll
            for (int i = 0; i < 2; ++i) {
                int row = arow + 32 * i;
                float4 av = *(const float4*)&F[(long)(n0 + row) * DIMS + dt * 32 + ac4 * 4];
                At[ac4 * 4 + 0][row] = av.x;
                At[ac4 * 4 + 1][row] = av.y;
                At[ac4 * 4 + 2][row] = av.z;
                At[ac4 * 4 + 3][row] = av.w;
            }
#pragma unroll
            for (int i = 0; i < 8; ++i) {
                int idx = tid + 256 * i;
                int d  = idx >> 6;
                int c4 = idx & 63;
                float4 bv = *(const float4*)&C[(long)(dt * 32 + d) * KC + kt * 256 + c4 * 4];
                *(float4*)&Bs[d * 256 + c4 * 4] = bv;
            }
            __syncthreads();

#pragma unroll 8
            for (int dd = 0; dd < 32; ++dd) {
                float4 a0 = *(const float4*)(Atp + dd * 68);
                float4 a1 = *(const float4*)(Atp + dd * 68 + 4);
                float4 b0 = *(const float4*)(Bsp + dd * 256);
                float4 b1 = *(const float4*)(Bsp + dd * 256 + 128);
                float a[8] = {a0.x, a0.y, a0.z, a0.w, a1.x, a1.y, a1.z, a1.w};
                float bb[8] = {b0.x, b0.y, b0.z, b0.w, b1.x, b1.y, b1.z, b1.w};
#pragma unroll
                for (int r = 0; r < 8; ++r)
#pragma unroll
                    for (int j = 0; j < 8; ++j)
                        acc[r][j] = fmaf(a[r], bb[j], acc[r][j]);
            }
        }

        float4 cs0 = *(const float4*)&csq[kt * 256 + tx * 4];
        float4 cs1 = *(const float4*)&csq[kt * 256 + 128 + tx * 4];
        float cs[8] = {cs0.x, cs0.y, cs0.z, cs0.w, cs1.x, cs1.y, cs1.z, cs1.w};
#pragma unroll
        for (int j = 0; j < 8; ++j) {
            int k = kt * 256 + ((j < 4) ? (tx * 4 + j) : (128 + tx * 4 + (j - 4)));
#pragma unroll
            for (int r = 0; r < 8; ++r) {
                float val = cs[j] - 2.0f * acc[r][j];
                u64 key = ((u64)f2o(val) << 32) | (u64)(unsigned)k;
                if (key < best[r]) best[r] = key;
            }
        }
    }

#pragma unroll
    for (int r = 0; r < 8; ++r)
        atomicMin(&best_row[ty * 8 + r], best[r]);
    __syncthreads();

    if (tid < 64)
        out[n0 + tid] = (float)(unsigned)(best_row[tid] & 0xFFFFFFFFull);
}

// ================= launch =================
extern "C" void kernel_launch(void* const* d_in, const int* in_sizes, int n_in,
                              void* d_out, int out_size, void* d_ws, size_t ws_size,
                              hipStream_t stream) {
    const float* F = (const float*)d_in[0];   // [131072, 512]
    const float* C = (const float*)d_in[1];   // [512, 1024]
    float* out = (float*)d_out;               // [131072]
    char* ws = (char*)d_ws;

    if (ws_size < WS_NEEDED) {
        float* csq = (float*)d_ws;
        csq_kernel<<<KC / 256, 256, 0, stream>>>(C, csq);
        assign_kernel_fp32<<<NPTS / 64, 256, 0, stream>>>(F, C, csq, out);
        return;
    }

    u16* Fhi  = (u16*)(ws + F_HI_OFF);
    u16* Flo  = (u16*)(ws + F_LO_OFF);
    u16* Cthi = (u16*)(ws + CT_HI_OFF);
    u16* Ctlo = (u16*)(ws + CT_LO_OFF);
    float* csq = (float*)(ws + CSQ_OFF);
    u32* g1 = (u32*)(ws + G1_OFF);
    u32* g2 = (u32*)(ws + G2_OFF);
    u32* cnt  = (u32*)(ws + CNT_OFF);   // overlays Fhi, used only after gemm
    u32* list = (u32*)(ws + LIST_OFF);

    split_f_kernel<<<NPTS * DIMS / 8 / 256, 256, 0, stream>>>((const float4*)F, Fhi, Flo);
    split_c_kernel<<<dim3(KC / 32, DIMS / 32), 256, 0, stream>>>(C, Cthi, Ctlo);
    csq_kernel<<<KC / 256, 256, 0, stream>>>(C, csq);
    hipMemsetAsync(g1, 0xFF, 2ull * NPTS * 4, stream);
    gemm_argmin_kernel<<<dim3(KC / 128, NPTS / 128), 256, 0, stream>>>(Fhi, Flo, Cthi, Ctlo, csq, g1, g2);
    // Fhi region dead from here; cnt[0]=list count, cnt[1]=work pointer
    hipMemsetAsync(ws + CNT_OFF, 0, 8, stream);
    flag_compact_kernel<<<NPTS / 256, 256, 0, stream>>>(g1, g2, out, cnt, list);
    rescue2_kernel<<<1024, 256, 0, stream>>>(F, C, csq, cnt, cnt + 1, out);
}

// Round 5
// 876.772 us; speedup vs baseline: 2.1327x; 1.1798x over previous
//
#include <hip/hip_runtime.h>
#include <hip/hip_bf16.h>

#define NPTS 131072
#define DIMS 512
#define KC   1024

using bf16x8 = __attribute__((ext_vector_type(8))) __bf16;
using f32x16 = __attribute__((ext_vector_type(16))) float;
typedef unsigned short u16;
typedef unsigned int u32;
typedef unsigned long long u64;

// ---- workspace layout (bytes) ----
#define CT_HI_OFF  0ull
#define CT_LO_OFF  1048576ull
#define CSQ_OFF    2097152ull      // 4 KB
#define CSQP_OFF   2101248ull      // 16 x 1024 floats = 64 KB
#define G1_OFF     2166784ull      // 512 KB
#define G2_OFF     2691072ull      // 512 KB
#define CNT_OFF    3215360ull      // 256 B
#define LIST_OFF   3215616ull      // 512 KB
#define WS_NEEDED  3739904ull

#define MARGIN 0.375f

// ---------- helpers ----------
__device__ __forceinline__ u16 f2bf(float v) {
    __hip_bfloat16 h = __float2bfloat16(v);
    return *reinterpret_cast<u16*>(&h);
}
__device__ __forceinline__ float bf2f(u16 u) {
    __hip_bfloat16 h = *reinterpret_cast<__hip_bfloat16*>(&u);
    return __bfloat162float(h);
}
__device__ __forceinline__ u32 f2o(float f) {
    u32 u = __float_as_uint(f);
    return (u & 0x80000000u) ? ~u : (u | 0x80000000u);
}
__device__ __forceinline__ float o2f(u32 o) {
    u32 u = (o & 0x80000000u) ? (o & 0x7FFFFFFFu) : ~o;
    return __uint_as_float(u);
}
__device__ __forceinline__ u32 umin32(u32 a, u32 b) { return a < b ? a : b; }
__device__ __forceinline__ u32 umax32(u32 a, u32 b) { return a > b ? a : b; }
__device__ __forceinline__ u64 umin64(u64 a, u64 b) { return a < b ? a : b; }

__device__ __forceinline__ void async_load16(const void* g, const void* l) {
    auto gp = reinterpret_cast<__attribute__((address_space(1))) void*>(
        reinterpret_cast<uintptr_t>(g));
    auto lp = reinterpret_cast<__attribute__((address_space(3))) void*>(
        (unsigned int)reinterpret_cast<uintptr_t>(l));
    __builtin_amdgcn_global_load_lds(gp, lp, 16, 0, 0);
}

// ---------- prepass: transpose C -> Ct [1024][512] hi/lo + csq partials ----------
__global__ void split_c_kernel(const float* __restrict__ C,
                               u16* __restrict__ hi, u16* __restrict__ lo,
                               float* __restrict__ csq_part) {
    __shared__ float t[32][33];
    int bn = blockIdx.x, bd = blockIdx.y;
    int tx = threadIdx.x & 31, ty = threadIdx.x >> 5;
#pragma unroll
    for (int r = 0; r < 32; r += 8)
        t[ty + r][tx] = C[(size_t)(bd * 32 + ty + r) * KC + bn * 32 + tx];
    __syncthreads();
#pragma unroll
    for (int r = 0; r < 32; r += 8) {
        int n = bn * 32 + ty + r, d = bd * 32 + tx;
        float v = t[tx][ty + r];
        u16 h = f2bf(v);
        u16 l = f2bf(v - bf2f(h));
        hi[(size_t)n * DIMS + d] = h;
        lo[(size_t)n * DIMS + d] = l;
        // deterministic 32-lane reduction of v^2 over tx (d within this tile)
        float sq = v * v;
#pragma unroll
        for (int m = 1; m < 32; m <<= 1)
            sq += __shfl_xor(sq, m, 64);
        if (tx == 0) csq_part[bd * KC + n] = sq;
    }
}

// ---------- csq: deterministic 16-part reduce ----------
__global__ void csq_reduce_kernel(const float* __restrict__ part, float* __restrict__ csq) {
    int k = blockIdx.x * 256 + threadIdx.x;
    float s = 0.f;
#pragma unroll
    for (int p = 0; p < 16; ++p) s += part[p * KC + k];
    csq[k] = s;
}

// ---------- fallback-only csq ----------
__global__ void csq_kernel(const float* __restrict__ C, float* __restrict__ csq) {
    int k = blockIdx.x * blockDim.x + threadIdx.x;
    if (k < KC) {
        float s = 0.f;
        for (int d = 0; d < DIMS; ++d) {
            float v = C[d * KC + k];
            s = fmaf(v, v, s);
        }
        csq[k] = s;
    }
}

// ---------- main: bf16x3 MFMA GEMM + block top-2 + global streaming top-2 ----------
// block 128(M) x 256(N), BK=32. 4 waves, wave tile 64x128 (2 mt x 4 nt of 32x32).
// A staged from fp32 F with in-kernel hi/lo split (VALU); B via global_load_lds.
// LDS: A_HI[0,8K) A_LO[8K,16K) B_HI[16K,32K) B_LO[32K,48K)
// 16B chunk swizzle: chunk(row,c) at row*64 + (c ^ ((row>>1)&3))*16
__global__ __launch_bounds__(256, 2) void gemm_argmin_kernel(
    const float* __restrict__ F,
    const u16* __restrict__ Cthi, const u16* __restrict__ Ctlo,
    const float* __restrict__ csq, u32* __restrict__ g1, u32* __restrict__ g2)
{
    __shared__ __align__(16) uint8_t smem[49152];

    const int tid  = threadIdx.x;
    const int lane = tid & 63;
    const int wid  = tid >> 6;
    const int wm   = wid >> 1, wn = wid & 1;
    // XCD swizzle: all 4 bx of one by land on the same XCD (linear%8 heuristic)
    const unsigned L = blockIdx.x;
    const int by = (int)((L & 7u) + 8u * (L >> 5));
    const int bx = (int)((L >> 3) & 3u);

    f32x16 acc[2][4];
#pragma unroll
    for (int i = 0; i < 2; ++i)
#pragma unroll
        for (int j = 0; j < 4; ++j)
#pragma unroll
            for (int e = 0; e < 16; ++e) acc[i][j][e] = 0.f;

    // --- A staging (VALU split): thread -> row=tid>>1 (0..127), half=tid&1 (chunks 2h,2h+1)
    const int arow = tid >> 1, ahalf = tid & 1;
    const float* aF = F + (size_t)(by * 128 + arow) * DIMS + ahalf * 16;
    const int axr = (arow >> 1) & 3;
    const unsigned aw0 = (unsigned)(arow * 64 + (((ahalf * 2 + 0) ^ axr) * 16));
    const unsigned aw1 = (unsigned)(arow * 64 + (((ahalf * 2 + 1) ^ axr) * 16));

    // --- B staging (async, 8 calls/wave): groups of 16 cols
    const int c_st = (lane & 3) ^ ((lane >> 3) & 3);
    const u16* bHbase = Cthi + (size_t)(bx * 256 + (lane >> 2)) * DIMS + c_st * 8;
    const u16* bLbase = Ctlo + (size_t)(bx * 256 + (lane >> 2)) * DIMS + c_st * 8;
    unsigned gcol[4];
    size_t goff[4];
#pragma unroll
    for (int g = 0; g < 4; ++g) {
        gcol[g] = (unsigned)(wid * 32 + (g & 1) * 16 + (g >> 1) * 128);
        goff[g] = (size_t)gcol[g] * DIMS;
    }

    // --- fragment read offsets ---
    const int kh = lane >> 5;                  // k-half within 16-k step
    const int xr = ((lane & 31) >> 1) & 3;
    const unsigned mbase = (unsigned)(lane & 31) * 64;
    const unsigned offs0 = mbase + (unsigned)(((0 + kh) ^ xr) * 16);   // s=0
    const unsigned offs1 = mbase + (unsigned)(((2 + kh) ^ xr) * 16);   // s=1

    for (int kt = 0; kt < DIMS / 32; ++kt) {
        const int k0 = kt * 32;
        // A global loads early (regs only, no LDS hazard)
        float4 f0 = *(const float4*)(aF + k0);
        float4 f1 = *(const float4*)(aF + k0 + 4);
        float4 f2 = *(const float4*)(aF + k0 + 8);
        float4 f3 = *(const float4*)(aF + k0 + 12);

        __syncthreads();   // prev iter's frag reads done
        // B: 8 async 16B-per-lane loads
#pragma unroll
        for (int g = 0; g < 4; ++g) {
            async_load16(bHbase + goff[g] + k0, smem + 16384 + gcol[g] * 64);
            async_load16(bLbase + goff[g] + k0, smem + 32768 + gcol[g] * 64);
        }
        // A: split into hi/lo, write swizzled chunks
        {
            float v[16] = {f0.x, f0.y, f0.z, f0.w, f1.x, f1.y, f1.z, f1.w,
                           f2.x, f2.y, f2.z, f2.w, f3.x, f3.y, f3.z, f3.w};
            bf16x8 h0, h1, l0, l1;
#pragma unroll
            for (int i = 0; i < 8; ++i) {
                __bf16 hb = (__bf16)v[i];
                h0[i] = hb; l0[i] = (__bf16)(v[i] - (float)hb);
            }
#pragma unroll
            for (int i = 0; i < 8; ++i) {
                __bf16 hb = (__bf16)v[8 + i];
                h1[i] = hb; l1[i] = (__bf16)(v[8 + i] - (float)hb);
            }
            *(bf16x8*)(smem + aw0) = h0;
            *(bf16x8*)(smem + aw1) = h1;
            *(bf16x8*)(smem + 8192 + aw0) = l0;
            *(bf16x8*)(smem + 8192 + aw1) = l1;
        }
        __syncthreads();   // stage visible

#pragma unroll
        for (int s = 0; s < 2; ++s) {
            const unsigned off = s ? offs1 : offs0;
            bf16x8 ah[2], al[2], bh[4], bl[4];
#pragma unroll
            for (int mt = 0; mt < 2; ++mt) {
                ah[mt] = *(const bf16x8*)(smem + wm * 4096 + mt * 2048 + off);
                al[mt] = *(const bf16x8*)(smem + 8192 + wm * 4096 + mt * 2048 + off);
            }
#pragma unroll
            for (int nt = 0; nt < 4; ++nt) {
                bh[nt] = *(const bf16x8*)(smem + 16384 + wn * 8192 + nt * 2048 + off);
                bl[nt] = *(const bf16x8*)(smem + 32768 + wn * 8192 + nt * 2048 + off);
            }
#pragma unroll
            for (int mt = 0; mt < 2; ++mt)
#pragma unroll
                for (int nt = 0; nt < 4; ++nt) {
                    acc[mt][nt] = __builtin_amdgcn_mfma_f32_32x32x16_bf16(ah[mt], bh[nt], acc[mt][nt], 0, 0, 0);
                    acc[mt][nt] = __builtin_amdgcn_mfma_f32_32x32x16_bf16(ah[mt], bl[nt], acc[mt][nt], 0, 0, 0);
                    acc[mt][nt] = __builtin_amdgcn_mfma_f32_32x32x16_bf16(al[mt], bh[nt], acc[mt][nt], 0, 0, 0);
                }
        }
    }

    __syncthreads();                 // all frag reads done before tbl overlay
    u32* tbl = (u32*)smem;           // [128][wn:2][top2:2]

    // C/D layout: col = lane&31, row = (reg&3) + 8*(reg>>2) + 4*(lane>>5)
    const int cl = lane & 31;
    const int col0 = bx * 256 + wn * 128 + cl;
    float cs[4];
#pragma unroll
    for (int nt = 0; nt < 4; ++nt) cs[nt] = csq[col0 + nt * 32];

#pragma unroll
    for (int mt = 0; mt < 2; ++mt)
#pragma unroll
        for (int reg = 0; reg < 16; ++reg) {
            const int row = wm * 64 + mt * 32 + (reg & 3) + 8 * (reg >> 2) + 4 * kh;
            u32 k[4];
#pragma unroll
            for (int nt = 0; nt < 4; ++nt) {
                float d = cs[nt] - 2.0f * acc[mt][nt][reg];
                k[nt] = (f2o(d) & 0xFFFFFC00u) | (u32)(col0 + nt * 32);
            }
            u32 m01 = umin32(k[0], k[1]), M01 = umax32(k[0], k[1]);
            u32 m23 = umin32(k[2], k[3]), M23 = umax32(k[2], k[3]);
            u32 a = umin32(m01, m23);
            u32 b = umin32(umax32(m01, m23), umin32(M01, M23));
#pragma unroll
            for (int off = 16; off > 0; off >>= 1) {
                u32 oa = __shfl_xor(a, off, 64);
                u32 ob = __shfl_xor(b, off, 64);
                u32 lo = umin32(a, oa), hi = umax32(a, oa);
                b = umin32(hi, umin32(b, ob));
                a = lo;
            }
            if (cl == 0) { tbl[row * 4 + wn * 2] = a; tbl[row * 4 + wn * 2 + 1] = b; }
        }
    __syncthreads();

    if (tid < 128) {
        const u32 a0 = tbl[tid * 4 + 0], b0 = tbl[tid * 4 + 1];
        const u32 a1 = tbl[tid * 4 + 2], b1 = tbl[tid * 4 + 3];
        u32 m1 = umin32(a0, a1);
        u32 m2 = umin32(umax32(a0, a1), umin32(b0, b1));
        const size_t grow = (size_t)by * 128 + tid;
        u32 o = atomicMin(&g1[grow], m1);
        atomicMin(&g2[grow], (m1 < o) ? o : m1);
        atomicMin(&g2[grow], m2);
    }
}

// ---------- phase A: flag rows; write confident outputs; compact doubtful rows ----------
__global__ __launch_bounds__(256) void flag_compact_kernel(
    const u32* __restrict__ g1, const u32* __restrict__ g2,
    float* __restrict__ out, u32* __restrict__ cnt, u32* __restrict__ list)
{
    const int row = blockIdx.x * 256 + threadIdx.x;
    const u32 k1 = g1[row], k2 = g2[row];
    const float d1 = o2f(k1 & 0xFFFFFC00u);
    const float d2 = o2f(k2 & 0xFFFFFC00u);
    if (d2 - d1 > MARGIN) {
        out[row] = (float)(k1 & 1023u);
    } else {
        u32 idx = atomicAdd(cnt, 1u);
        list[idx] = (u32)row;
    }
}

// ---------- phase B: exact fp32 argmin for flagged rows (work-stealing, 4/batch) ----------
__global__ __launch_bounds__(256) void rescue2_kernel(
    const float* __restrict__ F, const float* __restrict__ C,
    const float* __restrict__ csq, const u32* __restrict__ cnt,
    const u32* __restrict__ list, u32* __restrict__ wptr, float* __restrict__ out)
{
    __shared__ float xs[4][512];
    __shared__ u64 wavemin[4][4];
    __shared__ int rows_s[4];

    const int tid = threadIdx.x;
    const int lane = tid & 63;
    const int wid = tid >> 6;
    const u32 n = cnt[0];

    for (;;) {
        __syncthreads();
        u32 base;
        if (tid == 0) {
            base = atomicAdd(wptr, 4u);
            rows_s[0] = (int)base;
        }
        __syncthreads();
        base = (u32)rows_s[0];
        if (base >= n) break;

        int rows[4];
#pragma unroll
        for (int j = 0; j < 4; ++j) {
            u32 idx = base + j;
            rows[j] = (int)list[idx < n ? idx : (n - 1)];
        }
#pragma unroll
        for (int j = 0; j < 4; ++j) {
            if (tid < 128)
                *(float4*)&xs[j][tid * 4] = *(const float4*)&F[(size_t)rows[j] * DIMS + tid * 4];
        }
        __syncthreads();

        float dot[4][4];
#pragma unroll
        for (int j = 0; j < 4; ++j)
#pragma unroll
            for (int q = 0; q < 4; ++q) dot[j][q] = 0.f;

#pragma unroll 4
        for (int d = 0; d < DIMS; ++d) {
            float cv[4];
#pragma unroll
            for (int q = 0; q < 4; ++q) cv[q] = C[d * KC + tid + 256 * q];
            float xv[4];
#pragma unroll
            for (int j = 0; j < 4; ++j) xv[j] = xs[j][d];
#pragma unroll
            for (int j = 0; j < 4; ++j)
#pragma unroll
                for (int q = 0; q < 4; ++q)
                    dot[j][q] = fmaf(xv[j], cv[q], dot[j][q]);
        }

#pragma unroll
        for (int j = 0; j < 4; ++j) {
            u64 best = ~0ull;
#pragma unroll
            for (int q = 0; q < 4; ++q) {
                const int k = tid + 256 * q;
                const float dist = csq[k] - 2.0f * dot[j][q];
                best = umin64(best, ((u64)f2o(dist) << 32) | (u32)k);
            }
#pragma unroll
            for (int off = 32; off > 0; off >>= 1)
                best = umin64(best, __shfl_xor(best, off, 64));
            if (lane == 0) wavemin[j][wid] = best;
        }
        __syncthreads();
        if (tid < 4) {
            const u32 idx = base + tid;
            if (idx < n) {
                u64 b = umin64(umin64(wavemin[tid][0], wavemin[tid][1]),
                               umin64(wavemin[tid][2], wavemin[tid][3]));
                out[list[idx]] = (float)(u32)(b & 0xFFFFFFFFull);
            }
        }
    }
}

// ================= fallback (fp32 vector path, used only if ws too small) =================
__global__ __launch_bounds__(256, 3) void assign_kernel_fp32(
    const float* __restrict__ F, const float* __restrict__ C,
    const float* __restrict__ csq, float* __restrict__ out)
{
    __shared__ float At[32][68];
    __shared__ float Bs[32 * 256];
    __shared__ u64 best_row[64];

    const int tid = threadIdx.x;
    const int tx = tid & 31;
    const int ty = tid >> 5;
    const int n0 = blockIdx.x * 64;

    if (tid < 64) best_row[tid] = ~0ull;

    u64 best[8];
#pragma unroll
    for (int r = 0; r < 8; ++r) best[r] = ~0ull;

    const int arow = tid >> 3;
    const int ac4  = tid & 7;
    const float* Atp = &At[0][ty * 8];
    const float* Bsp = &Bs[tx * 4];

    for (int kt = 0; kt < 4; ++kt) {
        float acc[8][8];
#pragma unroll
        for (int r = 0; r < 8; ++r)
#pragma unroll
            for (int j = 0; j < 8; ++j) acc[r][j] = 0.f;

        for (int dt = 0; dt < DIMS / 32; ++dt) {
            __syncthreads();
#pragma unroll
            for (int i = 0; i < 2; ++i) {
                int row = arow + 32 * i;
                float4 av = *(const float4*)&F[(long)(n0 + row) * DIMS + dt * 32 + ac4 * 4];
                At[ac4 * 4 + 0][row] = av.x;
                At[ac4 * 4 + 1][row] = av.y;
                At[ac4 * 4 + 2][row] = av.z;
                At[ac4 * 4 + 3][row] = av.w;
            }
#pragma unroll
            for (int i = 0; i < 8; ++i) {
                int idx = tid + 256 * i;
                int d  = idx >> 6;
                int c4 = idx & 63;
                float4 bv = *(const float4*)&C[(long)(dt * 32 + d) * KC + kt * 256 + c4 * 4];
                *(float4*)&Bs[d * 256 + c4 * 4] = bv;
            }
            __syncthreads();

#pragma unroll 8
            for (int dd = 0; dd < 32; ++dd) {
                float4 a0 = *(const float4*)(Atp + dd * 68);
                float4 a1 = *(const float4*)(Atp + dd * 68 + 4);
                float4 b0 = *(const float4*)(Bsp + dd * 256);
                float4 b1 = *(const float4*)(Bsp + dd * 256 + 128);
                float a[8] = {a0.x, a0.y, a0.z, a0.w, a1.x, a1.y, a1.z, a1.w};
                float bb[8] = {b0.x, b0.y, b0.z, b0.w, b1.x, b1.y, b1.z, b1.w};
#pragma unroll
                for (int r = 0; r < 8; ++r)
#pragma unroll
                    for (int j = 0; j < 8; ++j)
                        acc[r][j] = fmaf(a[r], bb[j], acc[r][j]);
            }
        }

        float4 cs0 = *(const float4*)&csq[kt * 256 + tx * 4];
        float4 cs1 = *(const float4*)&csq[kt * 256 + 128 + tx * 4];
        float cs[8] = {cs0.x, cs0.y, cs0.z, cs0.w, cs1.x, cs1.y, cs1.z, cs1.w};
#pragma unroll
        for (int j = 0; j < 8; ++j) {
            int k = kt * 256 + ((j < 4) ? (tx * 4 + j) : (128 + tx * 4 + (j - 4)));
#pragma unroll
            for (int r = 0; r < 8; ++r) {
                float val = cs[j] - 2.0f * acc[r][j];
                u64 key = ((u64)f2o(val) << 32) | (u64)(unsigned)k;
                if (key < best[r]) best[r] = key;
            }
        }
    }

#pragma unroll
    for (int r = 0; r < 8; ++r)
        atomicMin(&best_row[ty * 8 + r], best[r]);
    __syncthreads();

    if (tid < 64)
        out[n0 + tid] = (float)(unsigned)(best_row[tid] & 0xFFFFFFFFull);
}

// ================= launch =================
extern "C" void kernel_launch(void* const* d_in, const int* in_sizes, int n_in,
                              void* d_out, int out_size, void* d_ws, size_t ws_size,
                              hipStream_t stream) {
    const float* F = (const float*)d_in[0];   // [131072, 512]
    const float* C = (const float*)d_in[1];   // [512, 1024]
    float* out = (float*)d_out;               // [131072]
    char* ws = (char*)d_ws;

    if (ws_size < WS_NEEDED) {
        float* csq = (float*)d_ws;
        csq_kernel<<<KC / 256, 256, 0, stream>>>(C, csq);
        assign_kernel_fp32<<<NPTS / 64, 256, 0, stream>>>(F, C, csq, out);
        return;
    }

    u16* Cthi = (u16*)(ws + CT_HI_OFF);
    u16* Ctlo = (u16*)(ws + CT_LO_OFF);
    float* csq  = (float*)(ws + CSQ_OFF);
    float* csqp = (float*)(ws + CSQP_OFF);
    u32* g1 = (u32*)(ws + G1_OFF);
    u32* g2 = (u32*)(ws + G2_OFF);
    u32* cnt  = (u32*)(ws + CNT_OFF);
    u32* list = (u32*)(ws + LIST_OFF);

    hipMemsetAsync(g1, 0xFF, 2ull * NPTS * 4, stream);   // g1+g2 contiguous
    hipMemsetAsync(cnt, 0, 8, stream);
    split_c_kernel<<<dim3(KC / 32, DIMS / 32), 256, 0, stream>>>(C, Cthi, Ctlo, csqp);
    csq_reduce_kernel<<<KC / 256, 256, 0, stream>>>(csqp, csq);
    gemm_argmin_kernel<<<4096, 256, 0, stream>>>(F, Cthi, Ctlo, csq, g1, g2);
    flag_compact_kernel<<<NPTS / 256, 256, 0, stream>>>(g1, g2, out, cnt, list);
    rescue2_kernel<<<1024, 256, 0, stream>>>(F, C, csq, cnt, list, cnt + 1, out);
}

// Round 6
// 756.878 us; speedup vs baseline: 2.4705x; 1.1584x over previous
//
#include <hip/hip_runtime.h>
#include <hip/hip_bf16.h>

#define NPTS 131072
#define DIMS 512
#define KC   1024

typedef _Float16 f16;
using f16x8  = __attribute__((ext_vector_type(8))) _Float16;
using f32x16 = __attribute__((ext_vector_type(16))) float;
typedef unsigned short u16;
typedef unsigned int u32;
typedef unsigned long long u64;

// ---- workspace layout (bytes) ----
#define CT_OFF     0ull            // Ct [1024][512] fp16 = 1 MB
#define CSQ_OFF    1048576ull      // 4 KB
#define CSQP_OFF   1052672ull      // 16*1024 floats = 64 KB
#define G1_OFF     1118208ull      // u64 x 131072 = 1 MB
#define G2_OFF     2166784ull      // 1 MB
#define CNT_OFF    3215360ull      // 256 B
#define LIST_OFF   3215616ull      // 512 KB
#define WS_NEEDED  3739904ull

#define MARGIN 0.2f

// ---------- helpers ----------
__device__ __forceinline__ u32 f2o(float f) {
    u32 u = __float_as_uint(f);
    return (u & 0x80000000u) ? ~u : (u | 0x80000000u);
}
__device__ __forceinline__ float o2f(u32 o) {
    u32 u = (o & 0x80000000u) ? (o & 0x7FFFFFFFu) : ~o;
    return __uint_as_float(u);
}
__device__ __forceinline__ u64 umin64(u64 a, u64 b) { return a < b ? a : b; }
__device__ __forceinline__ u64 umax64(u64 a, u64 b) { return a > b ? a : b; }

// global -> LDS direct (16B per lane). LDS dest is wave-uniform base + lane*16.
__device__ __forceinline__ void async_load16(const void* g, const void* l) {
    auto gp = reinterpret_cast<__attribute__((address_space(1))) void*>(
        reinterpret_cast<uintptr_t>(g));
    auto lp = reinterpret_cast<__attribute__((address_space(3))) void*>(
        (unsigned int)reinterpret_cast<uintptr_t>(l));
    __builtin_amdgcn_global_load_lds(gp, lp, 16, 0, 0);
}

// ---------- prepass: transpose C [512][1024] -> Ct [1024][512] fp16 + csq partials ----------
__global__ void split_c_kernel(const float* __restrict__ C,
                               u16* __restrict__ ct, float* __restrict__ csq_part) {
    __shared__ float t[32][33];
    int bn = blockIdx.x, bd = blockIdx.y;
    int tx = threadIdx.x & 31, ty = threadIdx.x >> 5;
#pragma unroll
    for (int r = 0; r < 32; r += 8)
        t[ty + r][tx] = C[(size_t)(bd * 32 + ty + r) * KC + bn * 32 + tx];
    __syncthreads();
#pragma unroll
    for (int r = 0; r < 32; r += 8) {
        int n = bn * 32 + ty + r, d = bd * 32 + tx;
        float v = t[tx][ty + r];
        f16 h = (f16)v;
        ct[(size_t)n * DIMS + d] = *reinterpret_cast<u16*>(&h);
        float sq = v * v;
#pragma unroll
        for (int m = 1; m < 32; m <<= 1)
            sq += __shfl_xor(sq, m, 64);
        if (tx == 0) csq_part[bd * KC + n] = sq;
    }
}

// ---------- csq: deterministic 16-part reduce ----------
__global__ void csq_reduce_kernel(const float* __restrict__ part, float* __restrict__ csq) {
    int k = blockIdx.x * 256 + threadIdx.x;
    float s = 0.f;
#pragma unroll
    for (int p = 0; p < 16; ++p) s += part[p * KC + k];
    csq[k] = s;
}

// ---------- fallback-only csq ----------
__global__ void csq_kernel(const float* __restrict__ C, float* __restrict__ csq) {
    int k = blockIdx.x * blockDim.x + threadIdx.x;
    if (k < KC) {
        float s = 0.f;
        for (int d = 0; d < DIMS; ++d) {
            float v = C[d * KC + k];
            s = fmaf(v, v, s);
        }
        csq[k] = s;
    }
}

// ---------- main: fp16 1-term MFMA GEMM + block top-2 + global streaming top-2 ----------
// block 128(M) x 128(N), BK=32, 16 kt. 4 waves 2x2, wave tile 64x64 (2mt x 2nt of 32x32x16).
// A converted fp32->fp16 in-kernel; B staged via global_load_lds from fp16 Ct.
// LDS: A[0,8K) row*64B, B[8K,16K) col*64B. 16B chunks, pos = c ^ ((row>>1)&3).
__global__ __launch_bounds__(256, 4) void gemm_argmin_kernel(
    const float* __restrict__ F, const u16* __restrict__ Ct,
    const float* __restrict__ csq, u64* __restrict__ g1, u64* __restrict__ g2)
{
    __shared__ __align__(16) uint8_t smem[16384];

    const int tid  = threadIdx.x;
    const int lane = tid & 63;
    const int wid  = tid >> 6;
    const int wm   = wid >> 1, wn = wid & 1;
    // XCD swizzle: XCD = L%8 = by%8 -> each XCD owns whole by-rows (A reused 8x via L2)
    const unsigned L = blockIdx.x;
    const int by = (int)((L & 7u) + 8u * (L >> 6));
    const int bx = (int)((L >> 3) & 7u);

    f32x16 acc[2][2];
#pragma unroll
    for (int i = 0; i < 2; ++i)
#pragma unroll
        for (int j = 0; j < 2; ++j)
#pragma unroll
            for (int e = 0; e < 16; ++e) acc[i][j][e] = 0.f;

    // --- A staging: thread -> row = tid>>1 (0..127), h = tid&1 (16 floats, chunks 2h, 2h+1)
    const int arow = tid >> 1, ah_ = tid & 1;
    const float* aF = F + (size_t)(by * 128 + arow) * DIMS + ah_ * 16;
    const int axr = (arow >> 1) & 3;
    const unsigned aw0 = (unsigned)(arow * 64 + (((ah_ * 2 + 0) ^ axr) * 16));
    const unsigned aw1 = (unsigned)(arow * 64 + (((ah_ * 2 + 1) ^ axr) * 16));

    // --- B staging: 2 async calls/wave, each 16 cols x 64B. lane -> col' = lane>>2, chunk c_st
    const int c_st = (lane & 3) ^ ((lane >> 3) & 3);
    const u16* bBase = Ct + (size_t)(bx * 128 + wid * 32 + (lane >> 2)) * DIMS + c_st * 8;
    const unsigned bw = 8192 + (unsigned)(wid * 32) * 64;   // + lane*16 implied

    // --- fragment read offsets ---
    const int kh = lane >> 5;
    const int cl = lane & 31;
    const int xr = (cl >> 1) & 3;
    const unsigned mb = (unsigned)cl * 64;
    const unsigned offs0 = mb + (unsigned)(((0 + kh) ^ xr) * 16);   // s=0: q=kh
    const unsigned offs1 = mb + (unsigned)(((2 + kh) ^ xr) * 16);   // s=1: q=2+kh

    for (int kt = 0; kt < DIMS / 32; ++kt) {
        const int k0 = kt * 32;
        // A global loads early (regs only)
        float4 f0 = *(const float4*)(aF + k0);
        float4 f1 = *(const float4*)(aF + k0 + 4);
        float4 f2 = *(const float4*)(aF + k0 + 8);
        float4 f3 = *(const float4*)(aF + k0 + 12);

        __syncthreads();   // prev iter frag reads done
        // B: 2 async 16B-per-lane loads (16 cols each)
        async_load16(bBase + k0,            smem + bw);
        async_load16(bBase + 16 * DIMS + k0, smem + bw + 1024);
        // A: convert + swizzled store
        {
            float v[16] = {f0.x, f0.y, f0.z, f0.w, f1.x, f1.y, f1.z, f1.w,
                           f2.x, f2.y, f2.z, f2.w, f3.x, f3.y, f3.z, f3.w};
            f16x8 h0, h1;
#pragma unroll
            for (int i = 0; i < 8; ++i) h0[i] = (f16)v[i];
#pragma unroll
            for (int i = 0; i < 8; ++i) h1[i] = (f16)v[8 + i];
            *(f16x8*)(smem + aw0) = h0;
            *(f16x8*)(smem + aw1) = h1;
        }
        __syncthreads();   // stage visible (drains vmcnt)

#pragma unroll
        for (int s = 0; s < 2; ++s) {
            const unsigned off = s ? offs1 : offs0;
            f16x8 a[2], b[2];
#pragma unroll
            for (int mt = 0; mt < 2; ++mt)
                a[mt] = *(const f16x8*)(smem + wm * 4096 + mt * 2048 + off);
#pragma unroll
            for (int nt = 0; nt < 2; ++nt)
                b[nt] = *(const f16x8*)(smem + 8192 + wn * 4096 + nt * 2048 + off);
#pragma unroll
            for (int mt = 0; mt < 2; ++mt)
#pragma unroll
                for (int nt = 0; nt < 2; ++nt)
                    acc[mt][nt] = __builtin_amdgcn_mfma_f32_32x32x16_f16(a[mt], b[nt], acc[mt][nt], 0, 0, 0);
        }
    }

    __syncthreads();
    u64* tbl = (u64*)smem;   // [128][wn:2][top2:2] = 4 KB

    // C/D layout: col = lane&31, row = (reg&3) + 8*(reg>>2) + 4*(lane>>5)
    const int colbase = bx * 128 + wn * 64 + cl;
    const float cs0 = csq[colbase], cs1 = csq[colbase + 32];

#pragma unroll
    for (int mt = 0; mt < 2; ++mt)
#pragma unroll
        for (int reg = 0; reg < 16; ++reg) {
            const int row = wm * 64 + mt * 32 + (reg & 3) + 8 * (reg >> 2) + 4 * kh;
            float d0 = cs0 - 2.0f * acc[mt][0][reg];
            float d1 = cs1 - 2.0f * acc[mt][1][reg];
            u64 k0 = ((u64)f2o(d0) << 32) | (u32)colbase;
            u64 k1 = ((u64)f2o(d1) << 32) | (u32)(colbase + 32);
            u64 a = umin64(k0, k1), b = umax64(k0, k1);
#pragma unroll
            for (int off = 16; off > 0; off >>= 1) {   // stays within 32-lane half
                u64 oa = __shfl_xor(a, off, 64);
                u64 ob = __shfl_xor(b, off, 64);
                u64 lo = umin64(a, oa), hi = umax64(a, oa);
                b = umin64(hi, umin64(b, ob));
                a = lo;
            }
            if (cl == 0) { tbl[(row * 2 + wn) * 2] = a; tbl[(row * 2 + wn) * 2 + 1] = b; }
        }
    __syncthreads();

    if (tid < 128) {
        const u64 a0 = tbl[tid * 4 + 0], b0 = tbl[tid * 4 + 1];
        const u64 a1 = tbl[tid * 4 + 2], b1 = tbl[tid * 4 + 3];
        u64 m1 = umin64(a0, a1);
        u64 m2 = umin64(umax64(a0, a1), umin64(b0, b1));
        const size_t grow = (size_t)by * 128 + tid;
        u64 o = atomicMin(&g1[grow], m1);
        atomicMin(&g2[grow], (m1 < o) ? o : m1);
        atomicMin(&g2[grow], m2);
    }
}

// ---------- phase A: flag rows; LDS-aggregated compaction (1 global atomic / block) ----------
__global__ __launch_bounds__(256) void flag_compact_kernel(
    const u64* __restrict__ g1, const u64* __restrict__ g2,
    float* __restrict__ out, u32* __restrict__ cnt, u32* __restrict__ list)
{
    __shared__ u32 lcnt, lbase;
    __shared__ u32 lrows[256];
    const int tid = threadIdx.x;
    const int row = blockIdx.x * 256 + tid;
    if (tid == 0) lcnt = 0;
    __syncthreads();

    const u64 k1 = g1[row], k2 = g2[row];
    const float d1 = o2f((u32)(k1 >> 32));
    const float d2 = o2f((u32)(k2 >> 32));
    bool flagged = !(d2 - d1 > MARGIN);
    if (!flagged) {
        out[row] = (float)(u32)(k1 & 1023u);
    } else {
        u32 li = atomicAdd(&lcnt, 1u);
        lrows[li] = (u32)row;
    }
    __syncthreads();
    if (tid == 0 && lcnt > 0) lbase = atomicAdd(cnt, lcnt);
    __syncthreads();
    if (tid < lcnt) list[lbase + tid] = lrows[tid];
}

// ---------- phase B: exact fp32 argmin for flagged rows (work-stealing, 4 rows/batch) ----------
__global__ __launch_bounds__(256) void rescue2_kernel(
    const float* __restrict__ F, const float* __restrict__ C,
    const float* __restrict__ csq, const u32* __restrict__ cnt,
    const u32* __restrict__ list, u32* __restrict__ wptr, float* __restrict__ out)
{
    __shared__ float xs[4][512];
    __shared__ u64 wavemin[4][4];
    __shared__ int rows_s[4];

    const int tid = threadIdx.x;
    const int lane = tid & 63;
    const int wid = tid >> 6;
    const u32 n = cnt[0];

    for (;;) {
        __syncthreads();
        u32 base;
        if (tid == 0) {
            base = atomicAdd(wptr, 4u);
            rows_s[0] = (int)base;
        }
        __syncthreads();
        base = (u32)rows_s[0];
        if (base >= n) break;

        int rows[4];
#pragma unroll
        for (int j = 0; j < 4; ++j) {
            u32 idx = base + j;
            rows[j] = (int)list[idx < n ? idx : (n - 1)];
        }
#pragma unroll
        for (int j = 0; j < 4; ++j) {
            if (tid < 128)
                *(float4*)&xs[j][tid * 4] = *(const float4*)&F[(size_t)rows[j] * DIMS + tid * 4];
        }
        __syncthreads();

        float dot[4][4];
#pragma unroll
        for (int j = 0; j < 4; ++j)
#pragma unroll
            for (int q = 0; q < 4; ++q) dot[j][q] = 0.f;

#pragma unroll 4
        for (int d = 0; d < DIMS; ++d) {
            float cv[4];
#pragma unroll
            for (int q = 0; q < 4; ++q) cv[q] = C[d * KC + tid + 256 * q];
            float xv[4];
#pragma unroll
            for (int j = 0; j < 4; ++j) xv[j] = xs[j][d];
#pragma unroll
            for (int j = 0; j < 4; ++j)
#pragma unroll
                for (int q = 0; q < 4; ++q)
                    dot[j][q] = fmaf(xv[j], cv[q], dot[j][q]);
        }

#pragma unroll
        for (int j = 0; j < 4; ++j) {
            u64 best = ~0ull;
#pragma unroll
            for (int q = 0; q < 4; ++q) {
                const int k = tid + 256 * q;
                const float dist = csq[k] - 2.0f * dot[j][q];
                best = umin64(best, ((u64)f2o(dist) << 32) | (u32)k);
            }
#pragma unroll
            for (int off = 32; off > 0; off >>= 1)
                best = umin64(best, __shfl_xor(best, off, 64));
            if (lane == 0) wavemin[j][wid] = best;
        }
        __syncthreads();
        if (tid < 4) {
            const u32 idx = base + tid;
            if (idx < n) {
                u64 b = umin64(umin64(wavemin[tid][0], wavemin[tid][1]),
                               umin64(wavemin[tid][2], wavemin[tid][3]));
                out[list[idx]] = (float)(u32)(b & 0xFFFFFFFFull);
            }
        }
    }
}

// ================= fallback (fp32 vector path, used only if ws too small) =================
__global__ __launch_bounds__(256, 3) void assign_kernel_fp32(
    const float* __restrict__ F, const float* __restrict__ C,
    const float* __restrict__ csq, float* __restrict__ out)
{
    __shared__ float At[32][68];
    __shared__ float Bs[32 * 256];
    __shared__ u64 best_row[64];

    const int tid = threadIdx.x;
    const int tx = tid & 31;
    const int ty = tid >> 5;
    const int n0 = blockIdx.x * 64;

    if (tid < 64) best_row[tid] = ~0ull;

    u64 best[8];
#pragma unroll
    for (int r = 0; r < 8; ++r) best[r] = ~0ull;

    const int arow = tid >> 3;
    const int ac4  = tid & 7;
    const float* Atp = &At[0][ty * 8];
    const float* Bsp = &Bs[tx * 4];

    for (int kt = 0; kt < 4; ++kt) {
        float acc[8][8];
#pragma unroll
        for (int r = 0; r < 8; ++r)
#pragma unroll
            for (int j = 0; j < 8; ++j) acc[r][j] = 0.f;

        for (int dt = 0; dt < DIMS / 32; ++dt) {
            __syncthreads();
#pragma unroll
            for (int i = 0; i < 2; ++i) {
                int row = arow + 32 * i;
                float4 av = *(const float4*)&F[(long)(n0 + row) * DIMS + dt * 32 + ac4 * 4];
                At[ac4 * 4 + 0][row] = av.x;
                At[ac4 * 4 + 1][row] = av.y;
                At[ac4 * 4 + 2][row] = av.z;
                At[ac4 * 4 + 3][row] = av.w;
            }
#pragma unroll
            for (int i = 0; i < 8; ++i) {
                int idx = tid + 256 * i;
                int d  = idx >> 6;
                int c4 = idx & 63;
                float4 bv = *(const float4*)&C[(long)(dt * 32 + d) * KC + kt * 256 + c4 * 4];
                *(float4*)&Bs[d * 256 + c4 * 4] = bv;
            }
            __syncthreads();

#pragma unroll 8
            for (int dd = 0; dd < 32; ++dd) {
                float4 a0 = *(const float4*)(Atp + dd * 68);
                float4 a1 = *(const float4*)(Atp + dd * 68 + 4);
                float4 b0 = *(const float4*)(Bsp + dd * 256);
                float4 b1 = *(const float4*)(Bsp + dd * 256 + 128);
                float a[8] = {a0.x, a0.y, a0.z, a0.w, a1.x, a1.y, a1.z, a1.w};
                float bb[8] = {b0.x, b0.y, b0.z, b0.w, b1.x, b1.y, b1.z, b1.w};
#pragma unroll
                for (int r = 0; r < 8; ++r)
#pragma unroll
                    for (int j = 0; j < 8; ++j)
                        acc[r][j] = fmaf(a[r], bb[j], acc[r][j]);
            }
        }

        float4 cs0 = *(const float4*)&csq[kt * 256 + tx * 4];
        float4 cs1 = *(const float4*)&csq[kt * 256 + 128 + tx * 4];
        float cs[8] = {cs0.x, cs0.y, cs0.z, cs0.w, cs1.x, cs1.y, cs1.z, cs1.w};
#pragma unroll
        for (int j = 0; j < 8; ++j) {
            int k = kt * 256 + ((j < 4) ? (tx * 4 + j) : (128 + tx * 4 + (j - 4)));
#pragma unroll
            for (int r = 0; r < 8; ++r) {
                float val = cs[j] - 2.0f * acc[r][j];
                u64 key = ((u64)f2o(val) << 32) | (u64)(unsigned)k;
                if (key < best[r]) best[r] = key;
            }
        }
    }

#pragma unroll
    for (int r = 0; r < 8; ++r)
        atomicMin(&best_row[ty * 8 + r], best[r]);
    __syncthreads();

    if (tid < 64)
        out[n0 + tid] = (float)(unsigned)(best_row[tid] & 0xFFFFFFFFull);
}

// ================= launch =================
extern "C" void kernel_launch(void* const* d_in, const int* in_sizes, int n_in,
                              void* d_out, int out_size, void* d_ws, size_t ws_size,
                              hipStream_t stream) {
    const float* F = (const float*)d_in[0];   // [131072, 512]
    const float* C = (const float*)d_in[1];   // [512, 1024]
    float* out = (float*)d_out;               // [131072]
    char* ws = (char*)d_ws;

    if (ws_size < WS_NEEDED) {
        float* csq = (float*)d_ws;
        csq_kernel<<<KC / 256, 256, 0, stream>>>(C, csq);
        assign_kernel_fp32<<<NPTS / 64, 256, 0, stream>>>(F, C, csq, out);
        return;
    }

    u16* Ct = (u16*)(ws + CT_OFF);
    float* csq  = (float*)(ws + CSQ_OFF);
    float* csqp = (float*)(ws + CSQP_OFF);
    u64* g1 = (u64*)(ws + G1_OFF);
    u64* g2 = (u64*)(ws + G2_OFF);
    u32* cnt  = (u32*)(ws + CNT_OFF);
    u32* list = (u32*)(ws + LIST_OFF);

    hipMemsetAsync(g1, 0xFF, 2ull * NPTS * 8, stream);   // g1+g2 contiguous
    hipMemsetAsync(cnt, 0, 8, stream);
    split_c_kernel<<<dim3(KC / 32, DIMS / 32), 256, 0, stream>>>(C, Ct, csqp);
    csq_reduce_kernel<<<KC / 256, 256, 0, stream>>>(csqp, csq);
    gemm_argmin_kernel<<<8192, 256, 0, stream>>>(F, Ct, csq, g1, g2);
    flag_compact_kernel<<<NPTS / 256, 256, 0, stream>>>(g1, g2, out, cnt, list);
    rescue2_kernel<<<1024, 256, 0, stream>>>(F, C, csq, cnt, list, cnt + 1, out);
}